// Round 1
// baseline (149.279 us; speedup 1.0000x reference)
//
#include <hip/hip_runtime.h>
#include <math.h>

#define HH 256
#define WW 256
#define BB 32
// map 0: pred > 0.5  (pred_bin == 1)
// map 1: pred <= 0.5 (pred_bin == 0)
// map 2: target == 1
// map 3: target == 0

// ---------------------------------------------------------------------------
// Kernel A: per-column 1D distance (exact), g = min(down, up, 512), stored u16.
// One block per (map, batch) image; thread w owns column w. Two serial passes
// over h; the down-distance is staged in the output buffer, mask bits kept in
// registers so pass 2 doesn't re-read the input.
// ---------------------------------------------------------------------------
__global__ __launch_bounds__(256) void edt_cols_kernel(
    const float* __restrict__ pred, const float* __restrict__ tgt,
    unsigned short* __restrict__ g /* [4][BB][HH][WW] */) {
  const int blk = blockIdx.x;          // 0..127
  const int m = blk >> 5;              // 0..3
  const int b = blk & 31;
  const int w = threadIdx.x;

  const float* in = ((m < 2) ? pred : tgt) + (size_t)b * (HH * WW);
  unsigned short* out = g + (size_t)(m * BB + b) * (HH * WW);

  unsigned int bits[HH / 32];
#pragma unroll
  for (int i = 0; i < HH / 32; ++i) bits[i] = 0u;

  int last = -(1 << 20);
  for (int h = 0; h < HH; ++h) {
    float v = in[h * WW + w];
    bool f;
    if (m == 0)      f = (v > 0.5f);
    else if (m == 1) f = !(v > 0.5f);
    else if (m == 2) f = (v == 1.0f);
    else             f = (v == 0.0f);
    if (f) { last = h; bits[h >> 5] |= (1u << (h & 31)); }
    int d = h - last;                      // huge if no feature yet
    out[h * WW + w] = (unsigned short)((d > 65535) ? 65535 : d);
  }

  int nxt = (1 << 20);
  for (int h = HH - 1; h >= 0; --h) {
    if (bits[h >> 5] & (1u << (h & 31))) nxt = h;
    int dd = (int)out[h * WW + w];
    int du = nxt - h;                      // huge if none below
    int gg = dd < du ? dd : du;
    gg = gg < 512 ? gg : 512;              // reference: min(g, H+W)
    out[h * WW + w] = (unsigned short)gg;
  }
}

// ---------------------------------------------------------------------------
// Kernel B: per-row min-plus with exact early exit + fused loss + block reduce.
// One block per (b, h) row; thread y computes D[h,y] for all 4 maps.
// Early exit is exact: candidates at offset k are >= k^2, and k^2 is monotone.
// ---------------------------------------------------------------------------
__global__ __launch_bounds__(256) void minplus_kernel(
    const unsigned short* __restrict__ g, float* __restrict__ partial) {
  const int row = blockIdx.x;              // b*HH + h
  const int y = threadIdx.x;
  const size_t mapStride = (size_t)BB * HH * WW;
  const size_t base = (size_t)row * WW;

  __shared__ float4 s[WW];
  {
    float g0 = (float)g[0 * mapStride + base + y];
    float g1 = (float)g[1 * mapStride + base + y];
    float g2 = (float)g[2 * mapStride + base + y];
    float g3 = (float)g[3 * mapStride + base + y];
    s[y] = make_float4(g0 * g0, g1 * g1, g2 * g2, g3 * g3);
  }
  __syncthreads();

  float4 me = s[y];
  float m0 = me.x, m1 = me.y, m2 = me.z, m3 = me.w;

  for (int k = 1; k < WW; ++k) {
    float c = (float)(k * k);
    float mx = fmaxf(fmaxf(m0, m1), fmaxf(m2, m3));
    if (c >= mx) break;                    // exact: further terms >= k^2
    int lo = y - k;
    if (lo >= 0) {
      float4 v = s[lo];
      m0 = fminf(m0, v.x + c);
      m1 = fminf(m1, v.y + c);
      m2 = fminf(m2, v.z + c);
      m3 = fminf(m3, v.w + c);
    }
    int hi = y + k;
    if (hi < WW) {
      float4 v = s[hi];
      m0 = fminf(m0, v.x + c);
      m1 = fminf(m1, v.y + c);
      m2 = fminf(m2, v.z + c);
      m3 = fminf(m3, v.w + c);
    }
  }

  float pd = sqrtf(m0) + sqrtf(m1);        // pred_dist
  float td = sqrtf(m2) + sqrtf(m3);        // target_dist
  float diff = pd - td;
  float val = diff * diff * td * td;       // (pd-td)^2 * td^ALPHA, ALPHA=2

  // block reduction: wave shuffle then cross-wave via LDS
  for (int off = 32; off > 0; off >>= 1) val += __shfl_down(val, off);
  __shared__ float wsum[4];
  if ((threadIdx.x & 63) == 0) wsum[threadIdx.x >> 6] = val;
  __syncthreads();
  if (threadIdx.x == 0)
    partial[row] = (wsum[0] + wsum[1]) + (wsum[2] + wsum[3]);
}

// ---------------------------------------------------------------------------
// Kernel C: reduce 8192 row partials in double, write mean.
// ---------------------------------------------------------------------------
__global__ __launch_bounds__(256) void finalize_kernel(
    const float* __restrict__ partial, float* __restrict__ out) {
  __shared__ double sd[256];
  double sum = 0.0;
  for (int i = threadIdx.x; i < BB * HH; i += 256) sum += (double)partial[i];
  sd[threadIdx.x] = sum;
  __syncthreads();
  for (int stride = 128; stride > 0; stride >>= 1) {
    if (threadIdx.x < stride) sd[threadIdx.x] += sd[threadIdx.x + stride];
    __syncthreads();
  }
  if (threadIdx.x == 0)
    out[0] = (float)(sd[0] / (double)((size_t)BB * HH * WW));
}

extern "C" void kernel_launch(void* const* d_in, const int* in_sizes, int n_in,
                              void* d_out, int out_size, void* d_ws, size_t ws_size,
                              hipStream_t stream) {
  const float* pred = (const float*)d_in[0];
  const float* tgt  = (const float*)d_in[1];
  float* out = (float*)d_out;

  // ws layout: [0, 16MB): u16 g distances [4][32][256][256]
  //            then 8192 floats of per-row partial sums
  unsigned short* g = (unsigned short*)d_ws;
  float* partial = (float*)((char*)d_ws +
                            (size_t)4 * BB * HH * WW * sizeof(unsigned short));

  hipLaunchKernelGGL(edt_cols_kernel, dim3(4 * BB), dim3(WW), 0, stream,
                     pred, tgt, g);
  hipLaunchKernelGGL(minplus_kernel, dim3(BB * HH), dim3(WW), 0, stream,
                     g, partial);
  hipLaunchKernelGGL(finalize_kernel, dim3(1), dim3(256), 0, stream,
                     partial, out);
}

// Round 2
// 44.862 us; speedup vs baseline: 3.3276x; 3.3276x over previous
//
#include <hip/hip_runtime.h>
#include <math.h>

#define HH 256
#define WW 256
#define BB 32
#define NW 8  // 256 rows = 8 x u32 words per column bitmask

// ---------------------------------------------------------------------------
// Kernel A: build column bitmasks.
//   P bit = (pred > 0.5), T bit = (target == 1.0)
// Complement masks (pred_bin==0, target==0) are derived by ~ in kernel B.
// Layout: [b][j][w] (w fastest) so both kernels' accesses are coalesced.
// Grid: BB*NW blocks; block (b,j) covers rows 32j..32j+31; thread w = column.
// ---------------------------------------------------------------------------
__global__ __launch_bounds__(256) void bitmask_kernel(
    const float* __restrict__ pred, const float* __restrict__ tgt,
    unsigned int* __restrict__ P, unsigned int* __restrict__ T) {
  const int b = blockIdx.x >> 3;
  const int j = blockIdx.x & 7;
  const int w = threadIdx.x;
  const float* pin = pred + (size_t)b * (HH * WW) + (j * 32) * WW + w;
  const float* tin = tgt  + (size_t)b * (HH * WW) + (j * 32) * WW + w;
  unsigned int pb = 0, tb = 0;
#pragma unroll
  for (int i = 0; i < 32; ++i) {
    pb |= (pin[i * WW] > 0.5f ? 1u : 0u) << i;
    tb |= (tin[i * WW] == 1.0f ? 1u : 0u) << i;
  }
  P[((size_t)b * NW + j) * WW + w] = pb;
  T[((size_t)b * NW + j) * WW + w] = tb;
}

// ---------------------------------------------------------------------------
// Kernel B: per-row fused pipeline.
// Block = (b, h). Thread w:
//   1. loads its column's 8-word P/T bitmasks (coalesced),
//   2. computes exact 1D distances for all 4 maps via branchless clz/ctz
//      scans (h is block-uniform -> mLE/mGE are scalar),
//   3. stages g^2 in LDS, runs the exact early-exit min-plus over the row,
//   4. computes the weighted loss term and block-reduces.
// ---------------------------------------------------------------------------
__global__ __launch_bounds__(256) void minplus_kernel(
    const unsigned int* __restrict__ P, const unsigned int* __restrict__ T,
    float* __restrict__ partial) {
  const int row = blockIdx.x;     // b*HH + h
  const int b = row >> 8;
  const int h = row & 255;
  const int y = threadIdx.x;      // column owned by this thread

  // position masks (block-uniform): bits at positions <= h / >= h
  const int wj = h >> 5, bi = h & 31;
  unsigned int mLE[NW], mGE[NW];
#pragma unroll
  for (int j = 0; j < NW; ++j) {
    mLE[j] = (j < wj) ? 0xFFFFFFFFu : ((j == wj) ? ((2u << bi) - 1u) : 0u);
    mGE[j] = (j > wj) ? 0xFFFFFFFFu : ((j == wj) ? ~((1u << bi) - 1u) : 0u);
  }

  unsigned int Pw[NW], Tw[NW];
#pragma unroll
  for (int j = 0; j < NW; ++j) {
    Pw[j] = P[((size_t)b * NW + j) * WW + y];
    Tw[j] = T[((size_t)b * NW + j) * WW + y];
  }

  // hi = highest set position <= h ; lo = lowest set position >= h
  int hi0 = -2000, hi1 = -2000, hi2 = -2000, hi3 = -2000;
  int lo0 = 2000, lo1 = 2000, lo2 = 2000, lo3 = 2000;
#pragma unroll
  for (int j = 0; j < NW; ++j) {   // ascending: last nonzero word wins
    unsigned int a;
    a = Pw[j] & mLE[j];  if (a) hi0 = 32 * j + 31 - __builtin_clz(a);
    a = ~Pw[j] & mLE[j]; if (a) hi1 = 32 * j + 31 - __builtin_clz(a);
    a = Tw[j] & mLE[j];  if (a) hi2 = 32 * j + 31 - __builtin_clz(a);
    a = ~Tw[j] & mLE[j]; if (a) hi3 = 32 * j + 31 - __builtin_clz(a);
  }
#pragma unroll
  for (int j = NW - 1; j >= 0; --j) {  // descending: first nonzero word wins
    unsigned int a;
    a = Pw[j] & mGE[j];  if (a) lo0 = 32 * j + __builtin_ctz(a);
    a = ~Pw[j] & mGE[j]; if (a) lo1 = 32 * j + __builtin_ctz(a);
    a = Tw[j] & mGE[j];  if (a) lo2 = 32 * j + __builtin_ctz(a);
    a = ~Tw[j] & mGE[j]; if (a) lo3 = 32 * j + __builtin_ctz(a);
  }

  int g0 = min(min(h - hi0, lo0 - h), 512);
  int g1 = min(min(h - hi1, lo1 - h), 512);
  int g2 = min(min(h - hi2, lo2 - h), 512);
  int g3 = min(min(h - hi3, lo3 - h), 512);

  __shared__ float4 s[WW];
  s[y] = make_float4((float)(g0 * g0), (float)(g1 * g1),
                     (float)(g2 * g2), (float)(g3 * g3));
  __syncthreads();

  float4 me = s[y];
  float m0 = me.x, m1 = me.y, m2 = me.z, m3 = me.w;

  for (int k = 1; k < WW; ++k) {
    float c = (float)(k * k);
    float mx = fmaxf(fmaxf(m0, m1), fmaxf(m2, m3));
    if (c >= mx) break;                 // exact: remaining candidates >= k^2
    int lo = y - k;
    if (lo >= 0) {
      float4 v = s[lo];
      m0 = fminf(m0, v.x + c); m1 = fminf(m1, v.y + c);
      m2 = fminf(m2, v.z + c); m3 = fminf(m3, v.w + c);
    }
    int hic = y + k;
    if (hic < WW) {
      float4 v = s[hic];
      m0 = fminf(m0, v.x + c); m1 = fminf(m1, v.y + c);
      m2 = fminf(m2, v.z + c); m3 = fminf(m3, v.w + c);
    }
  }

  float pd = sqrtf(m0) + sqrtf(m1);     // pred_dist
  float td = sqrtf(m2) + sqrtf(m3);     // target_dist
  float diff = pd - td;
  float val = diff * diff * td * td;    // (pd-td)^2 * td^ALPHA, ALPHA=2

  for (int off = 32; off > 0; off >>= 1) val += __shfl_down(val, off);
  __shared__ float wsum[4];
  if ((threadIdx.x & 63) == 0) wsum[threadIdx.x >> 6] = val;
  __syncthreads();
  if (threadIdx.x == 0)
    partial[row] = (wsum[0] + wsum[1]) + (wsum[2] + wsum[3]);
}

// ---------------------------------------------------------------------------
// Kernel C: reduce 8192 row partials in double, write mean.
// ---------------------------------------------------------------------------
__global__ __launch_bounds__(256) void finalize_kernel(
    const float* __restrict__ partial, float* __restrict__ out) {
  __shared__ double sd[256];
  double sum = 0.0;
  for (int i = threadIdx.x; i < BB * HH; i += 256) sum += (double)partial[i];
  sd[threadIdx.x] = sum;
  __syncthreads();
  for (int stride = 128; stride > 0; stride >>= 1) {
    if (threadIdx.x < stride) sd[threadIdx.x] += sd[threadIdx.x + stride];
    __syncthreads();
  }
  if (threadIdx.x == 0)
    out[0] = (float)(sd[0] / (double)((size_t)BB * HH * WW));
}

extern "C" void kernel_launch(void* const* d_in, const int* in_sizes, int n_in,
                              void* d_out, int out_size, void* d_ws, size_t ws_size,
                              hipStream_t stream) {
  const float* pred = (const float*)d_in[0];
  const float* tgt  = (const float*)d_in[1];
  float* out = (float*)d_out;

  // ws layout: P bitmasks (256 KB), T bitmasks (256 KB), partial (32 KB)
  unsigned int* P = (unsigned int*)d_ws;
  unsigned int* T = P + (size_t)BB * NW * WW;
  float* partial = (float*)(T + (size_t)BB * NW * WW);

  hipLaunchKernelGGL(bitmask_kernel, dim3(BB * NW), dim3(WW), 0, stream,
                     pred, tgt, P, T);
  hipLaunchKernelGGL(minplus_kernel, dim3(BB * HH), dim3(WW), 0, stream,
                     P, T, partial);
  hipLaunchKernelGGL(finalize_kernel, dim3(1), dim3(256), 0, stream,
                     partial, out);
}